// Round 1
// baseline (454.440 us; speedup 1.0000x reference)
//
#include <hip/hip_runtime.h>

#define NF 36
#define QN 100
#define TN 20
#define CN 92
#define NB 64

__global__ __launch_bounds__(128) void matcher_kernel(
    const float* __restrict__ logits,   // [64][3600][92]
    const float* __restrict__ pboxes,   // [64][3600][4]
    const int*   __restrict__ tlabels,  // [36][64][20]
    const float* __restrict__ tboxes,   // [36][64][20][4]
    float* __restrict__ out_cost,       // [64][36][100][20]
    float* __restrict__ out_pred,       // [64][36][20]
    float* __restrict__ out_tgt)        // [64][36][20]
{
    const int bf = blockIdx.x;          // b*36 + f
    const int b  = bf / NF;
    const int f  = bf % NF;
    const int tid = threadIdx.x;

    __shared__ float ben[TN][101];      // benefit[t][q] = -cost[q][t]; stride 101 -> conflict-free
    __shared__ float price[QN];
    __shared__ int   owner[QN];
    __shared__ int   obj_of[TN];
    __shared__ float bidv[TN];
    __shared__ int   bo[TN];
    __shared__ float bb[QN];
    __shared__ int   win[QN];
    __shared__ int   slab[TN];
    __shared__ float tbr[TN][4];        // raw cxcywh
    __shared__ float tbx[TN][4];        // xyxy
    __shared__ float tarea[TN];
    __shared__ float rmin[128], rmax[128];
    __shared__ float s_eps;
    __shared__ int   s_done;

    // ---- stage targets for this (f,b) ----
    if (tid < TN) {
        const int base = (f * NB + b) * TN + tid;
        slab[tid] = tlabels[base];
        const float* tb = tboxes + (size_t)base * 4;
        float cx = tb[0], cy = tb[1], w = tb[2], h = tb[3];
        tbr[tid][0] = cx; tbr[tid][1] = cy; tbr[tid][2] = w; tbr[tid][3] = h;
        float x1 = cx - 0.5f * w, y1 = cy - 0.5f * h;
        float x2 = cx + 0.5f * w, y2 = cy + 0.5f * h;
        tbx[tid][0] = x1; tbx[tid][1] = y1; tbx[tid][2] = x2; tbx[tid][3] = y2;
        tarea[tid] = (x2 - x1) * (y2 - y1);
        obj_of[tid] = -1;
    }
    if (tid < QN) { price[tid] = 0.f; owner[tid] = -1; bb[tid] = -INFINITY; win[tid] = TN; }
    float lmin = INFINITY, lmax = -INFINITY;
    __syncthreads();

    // ---- phase 1: cost matrix ----
    if (tid < QN) {
        const size_t row = (size_t)b * (NF * QN) + (size_t)f * QN + tid;
        const float* L = logits + row * CN;
        float m = -INFINITY;
        for (int c = 0; c < CN; ++c) m = fmaxf(m, L[c]);
        float s = 0.f;
        for (int c = 0; c < CN; ++c) s += expf(L[c] - m);

        const float* pb = pboxes + row * 4;
        float cx = pb[0], cy = pb[1], w = pb[2], h = pb[3];
        float px1 = cx - 0.5f * w, py1 = cy - 0.5f * h;
        float px2 = cx + 0.5f * w, py2 = cy + 0.5f * h;
        float a1 = (px2 - px1) * (py2 - py1);

        float* co = out_cost + ((size_t)bf * QN + tid) * TN;
        for (int t = 0; t < TN; ++t) {
            float p = expf(L[slab[t]] - m) / s;
            float cb = fabsf(cx - tbr[t][0]) + fabsf(cy - tbr[t][1]);
            cb = cb + fabsf(w - tbr[t][2]);
            cb = cb + fabsf(h - tbr[t][3]);
            float ltx = fmaxf(px1, tbx[t][0]), lty = fmaxf(py1, tbx[t][1]);
            float rbx = fminf(px2, tbx[t][2]), rby = fminf(py2, tbx[t][3]);
            float wx = fmaxf(rbx - ltx, 0.f), wy = fmaxf(rby - lty, 0.f);
            float inter = wx * wy;
            float uni = a1 + tarea[t] - inter;
            float iou = inter / uni;
            float ex1 = fminf(px1, tbx[t][0]), ey1 = fminf(py1, tbx[t][1]);
            float ex2 = fmaxf(px2, tbx[t][2]), ey2 = fmaxf(py2, tbx[t][3]);
            float ew = fmaxf(ex2 - ex1, 0.f), eh = fmaxf(ey2 - ey1, 0.f);
            float ae = ew * eh;
            float giou = iou - (ae - uni) / ae;
            float cost = (-p) + 5.0f * cb - 2.0f * giou;
            co[t] = cost;
            ben[t][tid] = -cost;
            lmin = fminf(lmin, cost);
            lmax = fmaxf(lmax, cost);
        }
    }
    rmin[tid] = lmin; rmax[tid] = lmax;
    __syncthreads();
    if (tid == 0) {
        float mn = INFINITY, mx = -INFINITY;
        for (int i = 0; i < 128; ++i) { mn = fminf(mn, rmin[i]); mx = fmaxf(mx, rmax[i]); }
        // spread = max(benefit) - min(benefit) + 1e-6 = (-mn) - (-mx) + 1e-6  (float-identical)
        float spread = (-mn) - (-mx) + 1e-6f;
        s_eps = spread / 1000.0f;
        s_done = 0;
    }

    // ---- phase 2: auction (Jacobi, exact reference dynamics) ----
    for (int it = 0; it < 20000; ++it) {
        __syncthreads();
        if (s_done) break;
        if (tid < TN) {
            if (obj_of[tid] < 0) {
                // top-2 of vals = benefit - price; strict '>' keeps lowest index on ties (top_k semantics)
                float v0 = -INFINITY, v1 = -INFINITY; int i0 = 0;
                const float* rowp = ben[tid];
                for (int q = 0; q < QN; ++q) {
                    float v = rowp[q] - price[q];
                    if (v > v0) { v1 = v0; v0 = v; i0 = q; }
                    else if (v > v1) { v1 = v; }
                }
                bidv[tid] = price[i0] + (v0 - v1) + s_eps;  // exact ref op order
                bo[tid] = i0;
            } else {
                bidv[tid] = -INFINITY;  // assigned targets don't bid
            }
        }
        __syncthreads();
        if (tid == 0) {
            // best_bid/winner: ascending t with strict '>' == .at[].max + .at[].min(t) tie-break
            for (int t = 0; t < TN; ++t) {
                float bd = bidv[t];
                if (bd != -INFINITY) {
                    int q = bo[t];
                    if (bd > bb[q]) { bb[q] = bd; win[q] = t; }
                }
            }
            for (int t = 0; t < TN; ++t) {
                if (bidv[t] != -INFINITY) {
                    int q = bo[t];
                    if (win[q] == t) {   // t wins q
                        int old = owner[q];
                        if (old >= 0) obj_of[old] = -1;   // evict
                        obj_of[t] = q;
                        owner[q] = t;
                        price[q] = bb[q];
                    }
                }
            }
            int done = 1;
            for (int t = 0; t < TN; ++t) {
                if (bidv[t] != -INFINITY) bb[bo[t]] = -INFINITY;  // reset touched entries
                if (obj_of[t] < 0) done = 0;
            }
            s_done = done;
        }
    }
    __syncthreads();

    // ---- phase 3: stable argsort of obj_of (rank computation) ----
    if (tid < TN) {
        int v = obj_of[tid];
        int r = 0;
        for (int u = 0; u < TN; ++u) {
            int w = obj_of[u];
            r += (w < v) || (w == v && u < tid);
        }
        out_pred[(size_t)bf * TN + r] = (float)v;
        out_tgt[(size_t)bf * TN + r]  = (float)tid;
    }
}

extern "C" void kernel_launch(void* const* d_in, const int* in_sizes, int n_in,
                              void* d_out, int out_size, void* d_ws, size_t ws_size,
                              hipStream_t stream) {
    const float* logits  = (const float*)d_in[0];
    const float* pboxes  = (const float*)d_in[1];
    const int*   tlabels = (const int*)d_in[2];
    const float* tboxes  = (const float*)d_in[3];

    float* out = (float*)d_out;
    float* out_cost = out;                                   // 64*36*100*20
    float* out_pred = out + (size_t)NB * NF * QN * TN;       // 64*36*20
    float* out_tgt  = out_pred + (size_t)NB * NF * TN;       // 64*36*20

    dim3 grid(NB * NF);
    dim3 block(128);
    hipLaunchKernelGGL(matcher_kernel, grid, block, 0, stream,
                       logits, pboxes, tlabels, tboxes, out_cost, out_pred, out_tgt);
}

// Round 2
// 211.165 us; speedup vs baseline: 2.1521x; 2.1521x over previous
//
#include <hip/hip_runtime.h>

#define NF 36
#define QN 100
#define TN 20
#define CN 92
#define NB 64

__global__ __launch_bounds__(128) void matcher_kernel(
    const float* __restrict__ logits,   // [64][3600][92]
    const float* __restrict__ pboxes,   // [64][3600][4]
    const int*   __restrict__ tlabels,  // [36][64][20]
    const float* __restrict__ tboxes,   // [36][64][20][4]
    float* __restrict__ out_cost,       // [64][36][100][20]
    float* __restrict__ out_pred,       // [64][36][20]
    float* __restrict__ out_tgt)        // [64][36][20]
{
    const int bf = blockIdx.x;          // b*36 + f
    const int b  = bf / NF;
    const int f  = bf % NF;
    const int tid = threadIdx.x;

    __shared__ float ben[TN][101];      // benefit[t][q] = -cost[q][t]; stride 101 -> conflict-free
    __shared__ float price[QN];
    __shared__ int   owner[QN];
    __shared__ int   obj_of[TN];
    __shared__ float bidv[TN];
    __shared__ int   bo[TN];
    __shared__ float bb[QN];
    __shared__ int   win[QN];
    __shared__ float pv0[100], pv1[100];
    __shared__ int   pi0[100];
    __shared__ int   slab[TN];
    __shared__ float tbr[TN][4];        // raw cxcywh
    __shared__ float tbx[TN][4];        // xyxy
    __shared__ float tarea[TN];
    __shared__ float rmin[128], rmax[128];
    __shared__ float s_eps;
    __shared__ int   s_un;              // # unassigned targets

    // ---- stage targets for this (f,b) ----
    if (tid < TN) {
        const int base = (f * NB + b) * TN + tid;
        slab[tid] = tlabels[base];
        const float* tb = tboxes + (size_t)base * 4;
        float cx = tb[0], cy = tb[1], w = tb[2], h = tb[3];
        tbr[tid][0] = cx; tbr[tid][1] = cy; tbr[tid][2] = w; tbr[tid][3] = h;
        float x1 = cx - 0.5f * w, y1 = cy - 0.5f * h;
        float x2 = cx + 0.5f * w, y2 = cy + 0.5f * h;
        tbx[tid][0] = x1; tbx[tid][1] = y1; tbx[tid][2] = x2; tbx[tid][3] = y2;
        tarea[tid] = (x2 - x1) * (y2 - y1);
        obj_of[tid] = -1;
    }
    if (tid < QN) { price[tid] = 0.f; owner[tid] = -1; }
    if (tid == 0) s_un = TN;
    float lmin = INFINITY, lmax = -INFINITY;
    __syncthreads();

    // ---- phase 1: cost matrix (vectorized logit reads) ----
    if (tid < QN) {
        const size_t row = (size_t)b * (NF * QN) + (size_t)f * QN + tid;
        const float* L = logits + row * CN;
        const float4* L4 = reinterpret_cast<const float4*>(L);   // 368B rows are 16B aligned
        // pass 1: max (same sequential order as scalar loop -> identical float result)
        float m = -INFINITY;
        #pragma unroll
        for (int i = 0; i < CN / 4; ++i) {
            float4 v = L4[i];
            m = fmaxf(m, v.x); m = fmaxf(m, v.y); m = fmaxf(m, v.z); m = fmaxf(m, v.w);
        }
        // pass 2: sum of exp (L1-warm), same sequential accumulate order
        float s = 0.f;
        #pragma unroll
        for (int i = 0; i < CN / 4; ++i) {
            float4 v = L4[i];
            s += expf(v.x - m); s += expf(v.y - m); s += expf(v.z - m); s += expf(v.w - m);
        }

        const float* pb = pboxes + row * 4;
        float cx = pb[0], cy = pb[1], w = pb[2], h = pb[3];
        float px1 = cx - 0.5f * w, py1 = cy - 0.5f * h;
        float px2 = cx + 0.5f * w, py2 = cy + 0.5f * h;
        float a1 = (px2 - px1) * (py2 - py1);

        for (int t = 0; t < TN; ++t) {
            float p = expf(L[slab[t]] - m) / s;     // scalar gather, L1/L2 warm
            float cb = fabsf(cx - tbr[t][0]) + fabsf(cy - tbr[t][1]);
            cb = cb + fabsf(w - tbr[t][2]);
            cb = cb + fabsf(h - tbr[t][3]);
            float ltx = fmaxf(px1, tbx[t][0]), lty = fmaxf(py1, tbx[t][1]);
            float rbx = fminf(px2, tbx[t][2]), rby = fminf(py2, tbx[t][3]);
            float wx = fmaxf(rbx - ltx, 0.f), wy = fmaxf(rby - lty, 0.f);
            float inter = wx * wy;
            float uni = a1 + tarea[t] - inter;
            float iou = inter / uni;
            float ex1 = fminf(px1, tbx[t][0]), ey1 = fminf(py1, tbx[t][1]);
            float ex2 = fmaxf(px2, tbx[t][2]), ey2 = fmaxf(py2, tbx[t][3]);
            float ew = fmaxf(ex2 - ex1, 0.f), eh = fmaxf(ey2 - ey1, 0.f);
            float ae = ew * eh;
            float giou = iou - (ae - uni) / ae;
            float cost = (-p) + 5.0f * cb - 2.0f * giou;
            ben[t][tid] = -cost;
            lmin = fminf(lmin, cost);
            lmax = fmaxf(lmax, cost);
        }
    }
    rmin[tid] = lmin; rmax[tid] = lmax;
    __syncthreads();

    // ---- coalesced cost write-out from LDS (kills partial-line writes) ----
    {
        float4* dst = reinterpret_cast<float4*>(out_cost + (size_t)bf * (QN * TN));
        for (int i = tid; i < (QN * TN) / 4; i += 128) {
            int k = i * 4;
            float4 v;
            v.x = -ben[(k + 0) % TN][(k + 0) / TN];
            v.y = -ben[(k + 1) % TN][(k + 1) / TN];
            v.z = -ben[(k + 2) % TN][(k + 2) / TN];
            v.w = -ben[(k + 3) % TN][(k + 3) / TN];
            dst[i] = v;
        }
    }
    if (tid == 0) {
        float mn = INFINITY, mx = -INFINITY;
        for (int i = 0; i < 128; ++i) { mn = fminf(mn, rmin[i]); mx = fmaxf(mx, rmax[i]); }
        // spread = max(benefit) - min(benefit) + 1e-6 = (-mn) - (-mx) + 1e-6  (float-identical)
        float spread = (-mn) - (-mx) + 1e-6f;
        s_eps = spread / 1000.0f;
    }

    // ---- phase 2: auction (Jacobi, exact reference dynamics, parallelized) ----
    for (int it = 0; it < 20000; ++it) {
        __syncthreads();                 // covers prev-iter updates + s_un
        if (s_un == 0) break;

        // bid partials: thread = bidder t (tid/5) x chunk j (tid%5), 20 q each
        if (tid < 100) {
            int t = tid / 5, j = tid % 5;
            if (obj_of[t] < 0) {
                int q0 = j * 20;
                float v0 = -INFINITY, v1 = -INFINITY; int i0 = q0;
                const float* rowp = ben[t];
                #pragma unroll
                for (int q = q0; q < q0 + 20; ++q) {
                    float v = rowp[q] - price[q];
                    if (v > v0) { v1 = v0; v0 = v; i0 = q; }
                    else if (v > v1) { v1 = v; }
                }
                pv0[tid] = v0; pv1[tid] = v1; pi0[tid] = i0;
            }
        }
        __syncthreads();

        // ordered 5-way merge per bidder (value- and tie-break-exact vs serial scan)
        if (tid < TN) {
            if (obj_of[tid] < 0) {
                int base = tid * 5;
                float v0 = pv0[base], v1 = pv1[base]; int i0 = pi0[base];
                #pragma unroll
                for (int j = 1; j < 5; ++j) {
                    float bv0 = pv0[base + j], bv1 = pv1[base + j]; int bi0 = pi0[base + j];
                    if (bv0 > v0) { v1 = fmaxf(v0, bv1); v0 = bv0; i0 = bi0; }
                    else          { v1 = fmaxf(bv0, v1); }
                }
                bidv[tid] = price[i0] + (v0 - v1) + s_eps;  // exact ref op order
                bo[tid] = i0;
            } else {
                bidv[tid] = -INFINITY;
            }
        }
        __syncthreads();

        // per-q best bid + winner (ascending t, strict '>' == min-t among max bidders)
        if (tid < QN) {
            float best = -INFINITY; int wt = TN;
            #pragma unroll
            for (int t = 0; t < TN; ++t) {
                float bd = bidv[t];                 // broadcast LDS read
                if (bd != -INFINITY && bo[t] == tid && bd > best) { best = bd; wt = t; }
            }
            bb[tid] = best; win[tid] = wt;
        }
        __syncthreads();

        // commit winners (race-free: winners were unassigned, evictees are assigned & distinct)
        if (tid < TN) {
            float bd = bidv[tid];
            if (bd != -INFINITY) {
                int q = bo[tid];
                if (win[q] == tid) {
                    int old = owner[q];
                    if (old >= 0) { obj_of[old] = -1; atomicAdd(&s_un, 1); }
                    obj_of[tid] = q;
                    owner[q] = tid;
                    price[q] = bb[q];
                    atomicSub(&s_un, 1);
                }
            }
        }
    }
    __syncthreads();

    // ---- phase 3: stable argsort of obj_of (rank computation) ----
    if (tid < TN) {
        int v = obj_of[tid];
        int r = 0;
        for (int u = 0; u < TN; ++u) {
            int w = obj_of[u];
            r += (w < v) || (w == v && u < tid);
        }
        out_pred[(size_t)bf * TN + r] = (float)v;
        out_tgt[(size_t)bf * TN + r]  = (float)tid;
    }
}

extern "C" void kernel_launch(void* const* d_in, const int* in_sizes, int n_in,
                              void* d_out, int out_size, void* d_ws, size_t ws_size,
                              hipStream_t stream) {
    const float* logits  = (const float*)d_in[0];
    const float* pboxes  = (const float*)d_in[1];
    const int*   tlabels = (const int*)d_in[2];
    const float* tboxes  = (const float*)d_in[3];

    float* out = (float*)d_out;
    float* out_cost = out;                                   // 64*36*100*20
    float* out_pred = out + (size_t)NB * NF * QN * TN;       // 64*36*20
    float* out_tgt  = out_pred + (size_t)NB * NF * TN;       // 64*36*20

    dim3 grid(NB * NF);
    dim3 block(128);
    hipLaunchKernelGGL(matcher_kernel, grid, block, 0, stream,
                       logits, pboxes, tlabels, tboxes, out_cost, out_pred, out_tgt);
}